// Round 17
// baseline (261.125 us; speedup 1.0000x reference)
//
#include <hip/hip_runtime.h>
#include <hip/hip_bf16.h>
#include <stdint.h>
#include <math.h>

#define BB 2
#define CC 512
#define HH 64
#define WW 64
#define LL 4096
#define DD 256
#define CIN 4608   // 512*9
#define NG 144     // gates = 16 c-chunks x 9 offsets

typedef _Float16 half_t;
typedef __attribute__((ext_vector_type(8))) _Float16 f16x8;
typedef __attribute__((ext_vector_type(4))) _Float16 f16x4;
typedef __attribute__((ext_vector_type(4))) float f32x4;

// ---------------- Kernel A: presplit images -> channel-last f16 hi/lo, swizzled
__global__ __launch_bounds__(256) void presplit(const float* __restrict__ query,
                                                const float* __restrict__ key,
                                                char* __restrict__ img_ts) {
    __shared__ float tile[32][65];
    int img = blockIdx.y;               // b = img&1, type = img>>1
    int y   = blockIdx.x;
    const float* src = ((img >> 1) ? key : query) + (size_t)(img & 1) * CC * LL + y * WW;
    char* dstbase = img_ts + ((size_t)img * 64 + y) * (16 * 64 * 128);
    int t = threadIdx.x;
    int xl = t & 63, c4 = t >> 6;
    int xw = t >> 2, fsw = t & 3;
    for (int cc = 0; cc < 16; ++cc) {
#pragma unroll
        for (int j = 0; j < 8; ++j) {
            int cl = c4 + j * 4;
            tile[cl][xl] = src[(size_t)(cc * 32 + cl) * LL + xl];
        }
        __syncthreads();
        f16x8 h8, l8;
#pragma unroll
        for (int j = 0; j < 8; ++j) {
            float v = tile[fsw * 8 + j][xw];
            half_t h = (half_t)v;
            h8[j] = h; l8[j] = (half_t)(v - (float)h);
        }
        char* p = dstbase + (size_t)cc * 8192 + xw * 128;
        int swz = (xw & 7) << 4;
        *(f16x8*)(p + ((fsw * 16) ^ swz)) = h8;
        *(f16x8*)(p + ((64 + fsw * 16) ^ swz)) = l8;
        __syncthreads();
    }
}

// ---------------- Kernel B: repack W into per-gate tiles [g = cc*9+o][d][128B]
__global__ __launch_bounds__(256) void splitW2b(const float* __restrict__ W,
                                                char* __restrict__ Wst) {
    int i = blockIdx.x * 256 + threadIdx.x;   // NG*DD*4 = 147456
    if (i >= NG * DD * 4) return;
    int g  = i >> 10;
    int r  = i & 1023;
    int d  = r >> 2;
    int fs = r & 3;
    int cc = g / 9, o = g - cc * 9;
    const float* src = W + (size_t)d * CIN;
    f16x8 h8, l8;
#pragma unroll
    for (int j = 0; j < 8; j++) {
        float w = src[(cc * 32 + fs * 8 + j) * 9 + o];
        half_t h = (half_t)w;
        h8[j] = h;
        l8[j] = (half_t)(w - (float)h);
    }
    size_t base = (size_t)g * 32768 + d * 128;
    int sw = (d & 7) << 4;
    *(f16x8*)(Wst + base + ((fs * 16) ^ sw)) = h8;
    *(f16x8*)(Wst + base + ((64 + fs * 16) ^ sw)) = l8;
}

// ---------------- Kernel 1: embed, offset-decomposed, K-split x2.
// Block 256d x 128l, 8 waves of 32d x 128l (wave-private W rows).
// 2-BODY-AHEAD pipeline. Correctness fences:
//  (1) prologue s_barrier AFTER each wave's vmcnt(4) retires its own B0/W0
//      writes and BEFORE the first RDB -> block-wide B0 visibility (the
//      round-15/16 NaN: prologue RDB raced other waves' B DMA).
//  (2) RDA/RDB split by sched_barrier(0) so the 4 A-reads are the OLDEST
//      lgkm ops; lgkmcnt(15) provably retires them before DMAW overwrites.
//  (3) chunk barrier at O==7 (lgkm(0)+s_barrier) fences cross-wave B
//      reads/overwrites; per-wave counted vmcnt fences wave-private W.
__global__ __launch_bounds__(512, 2) void embed_mfma(const char* __restrict__ img_ts,
                                                     const char* __restrict__ Wst,
                                                     const char* __restrict__ zp,
                                                     float* __restrict__ part) {
    __shared__ char sW[2][32768];       // W gate tiles; wave w owns bytes w*4096..+4095
    __shared__ char sB[2][33792];       // B tiles: [ri 4][xi 66][128B]

    int iid = blockIdx.y;               // image 0..3
    int ks  = blockIdx.z;               // K half 0..1
    int lt  = blockIdx.x;               // l-tile 0..31
    int y0  = lt * 2;
    int t = threadIdx.x;
    int w = t >> 6, lane = t & 63;
    int fr = lane & 15, fs = lane >> 4;

    const char* imgb = img_ts + (size_t)iid * (64 * 16 * 64 * 128) + (size_t)ks * 65536;
    const char *ps0, *ps1, *ps2, *ps3, *ps4;
    int pb0, pb1, pb2, pb3, pb4;
#define PREP(qv, PS, PB)                                                \
    {                                                                   \
        int q = (qv);                                                   \
        int ri = q / 528;                                               \
        int rem = q - ri * 528;                                         \
        int xi = rem >> 3, sub = rem & 7;                               \
        int xg = xi - 1, yg = y0 - 1 + ri;                              \
        bool ok = (yg >= 0) && (yg < 64) && (xg >= 0) && (xg < 64);     \
        PS = ok ? imgb + (size_t)yg * 131072 + (size_t)xg * 128 + sub * 16 \
                : zp + ((q & 255) * 16);                                \
        PB = ok ? 8192 : 0;                                             \
    }
    PREP(t, ps0, pb0); PREP(512 + t, ps1, pb1); PREP(1024 + t, ps2, pb2);
    PREP(1536 + t, ps3, pb3); PREP(2048 + t, ps4, pb4);

    const char* pWl = Wst + (size_t)ks * 72 * 32768 + (w << 12) + lane * 16;
    char* wdst0 = &sW[0][0] + (w << 12) + lane * 16;
    char* wdst1 = wdst0 + 32768;
    char* bB0 = &sB[0][0] + t * 16;

    int swzA = (fr & 7) << 4;
    const char* aBH = &sW[0][0] + (w << 12) + fr * 128 + ((fs * 16) ^ swzA);
    const char* aBL = &sW[0][0] + (w << 12) + fr * 128 + ((64 + fs * 16) ^ swzA);
    const char* bH0 = &sB[0][0] + (fr + 0) * 128 + ((fs * 16) ^ (((fr - 1) & 7) << 4));
    const char* bL0 = &sB[0][0] + (fr + 0) * 128 + (((64 + fs * 16)) ^ (((fr - 1) & 7) << 4));
    const char* bH1 = &sB[0][0] + (fr + 1) * 128 + ((fs * 16) ^ (((fr) & 7) << 4));
    const char* bL1 = &sB[0][0] + (fr + 1) * 128 + (((64 + fs * 16)) ^ (((fr) & 7) << 4));
    const char* bH2 = &sB[0][0] + (fr + 2) * 128 + ((fs * 16) ^ (((fr + 1) & 7) << 4));
    const char* bL2 = &sB[0][0] + (fr + 2) * 128 + (((64 + fs * 16)) ^ (((fr + 1) & 7) << 4));

#define GLL(src, dst)                                                   \
    __builtin_amdgcn_global_load_lds(                                   \
        (const __attribute__((address_space(1))) void*)(src),           \
        (__attribute__((address_space(3))) void*)(dst), 16, 0, 0)

#define DMAW(SEL)                                                       \
    do {                                                                \
        char* wd_ = (SEL) ? wdst1 : wdst0;                              \
        GLL(pWl, wd_);                                                  \
        GLL(pWl + 1024, wd_ + 1024);                                    \
        GLL(pWl + 2048, wd_ + 2048);                                    \
        GLL(pWl + 3072, wd_ + 3072);                                    \
        pWl += 32768;                                                   \
    } while (0)

#define DMAB(SEL)                                                       \
    do {                                                                \
        char* bd_ = bB0 + (SEL) * 33792;                                \
        GLL(ps0, bd_);                                                  \
        GLL(ps1, bd_ + 8192);                                           \
        GLL(ps2, bd_ + 16384);                                          \
        GLL(ps3, bd_ + 24576);                                          \
        if (t < 64) GLL(ps4, bd_ + 32768);                              \
        ps0 += pb0; ps1 += pb1; ps2 += pb2; ps3 += pb3; ps4 += pb4;     \
    } while (0)

#define RDA(AH, AL, BSEL)                                               \
    do {                                                                \
        AH[0] = *(const f16x8*)(aBH + (BSEL) * 32768);                  \
        AL[0] = *(const f16x8*)(aBL + (BSEL) * 32768);                  \
        AH[1] = *(const f16x8*)(aBH + 2048 + (BSEL) * 32768);           \
        AL[1] = *(const f16x8*)(aBL + 2048 + (BSEL) * 32768);           \
    } while (0)

#define RDB(BH, BL, DI, DJ, CSEL)                                       \
    do {                                                                \
        const char* h_ = (DJ) == 0 ? bH0 : (DJ) == 1 ? bH1 : bH2;       \
        const char* l_ = (DJ) == 0 ? bL0 : (DJ) == 1 ? bL1 : bL2;       \
        _Pragma("unroll")                                               \
        for (int cg = 0; cg < 8; cg++) {                                \
            int imm = ((cg >> 2) + (DI)) * 8448 + (cg & 3) * 2048 + (CSEL) * 33792; \
            BH[cg] = *(const f16x8*)(h_ + imm);                         \
            BL[cg] = *(const f16x8*)(l_ + imm);                         \
        }                                                               \
    } while (0)

#define DOMFMA(AH, AL, BH, BL)                                          \
    do {                                                                \
        _Pragma("unroll")                                               \
        for (int rg = 0; rg < 2; rg++)                                  \
            _Pragma("unroll")                                           \
            for (int cg = 0; cg < 8; cg++)                              \
                acc[rg][cg] = __builtin_amdgcn_mfma_f32_16x16x32_f16(AH[rg], BH[cg], acc[rg][cg], 0, 0, 0); \
        _Pragma("unroll")                                               \
        for (int rg = 0; rg < 2; rg++)                                  \
            _Pragma("unroll")                                           \
            for (int cg = 0; cg < 8; cg++) {                            \
                acc[rg][cg] = __builtin_amdgcn_mfma_f32_16x16x32_f16(AH[rg], BL[cg], acc[rg][cg], 0, 0, 0); \
                acc[rg][cg] = __builtin_amdgcn_mfma_f32_16x16x32_f16(AL[rg], BH[cg], acc[rg][cg], 0, 0, 0); \
            }                                                           \
    } while (0)

    f32x4 acc[2][8];
#pragma unroll
    for (int rg = 0; rg < 2; rg++)
#pragma unroll
        for (int cg = 0; cg < 8; cg++) acc[rg][cg] = (f32x4){0.f, 0.f, 0.f, 0.f};

    f16x8 ah0[2], al0[2], ah1[2], al1[2];
    f16x8 bh0[8], bl0[8], bh1[8], bl1[8];

    // ---- prologue
    DMAB(0);
    DMAW(0);
    DMAW(1);
    asm volatile("s_waitcnt vmcnt(4)" ::: "memory");   // own B0 + W0 retired; W1 flying
    __builtin_amdgcn_sched_barrier(0);
    __builtin_amdgcn_s_barrier();                      // ALL waves' B0 writes visible
    __builtin_amdgcn_sched_barrier(0);
    RDA(ah0, al0, 0);
    __builtin_amdgcn_sched_barrier(0);                 // A-reads oldest in lgkm queue
    RDB(bh0, bl0, 0, 0, 0);                            // frags(0): o=0
    asm volatile("s_waitcnt lgkmcnt(15)" ::: "memory"); // A(0) reads retired
    __builtin_amdgcn_sched_barrier(0);
    DMAW(0);                                           // W2 -> b0
    asm volatile("s_waitcnt vmcnt(4)" ::: "memory");   // W1 retired; W2 flying
    __builtin_amdgcn_sched_barrier(0);
    RDA(ah1, al1, 1);
    __builtin_amdgcn_sched_barrier(0);                 // A-reads oldest
    RDB(bh1, bl1, 0, 1, 0);                            // frags(1): o=1
    asm volatile("s_waitcnt lgkmcnt(15)" ::: "memory"); // A(1) reads retired
    __builtin_amdgcn_sched_barrier(0);
    DMAW(1);                                           // W3 -> b1

#define BODY(KK, O, CSEL2, DI2, DJ2, V8)                                \
    do {                                                                \
        if ((O) == 7) {                                                 \
            asm volatile("s_waitcnt lgkmcnt(0)" ::: "memory");          \
            __builtin_amdgcn_s_barrier();                               \
            __builtin_amdgcn_sched_barrier(0);                          \
        }                                                               \
        if ((KK) >= 15)                                                 \
            asm volatile("s_waitcnt vmcnt(0)" ::: "memory");            \
        else if (V8)                                                    \
            asm volatile("s_waitcnt vmcnt(8)" ::: "memory");            \
        else                                                            \
            asm volatile("s_waitcnt vmcnt(4)" ::: "memory");            \
        __builtin_amdgcn_sched_barrier(0);                              \
        if ((KK) & 1) DOMFMA(ah1, al1, bh1, bl1);                       \
        else          DOMFMA(ah0, al0, bh0, bl0);                       \
        __builtin_amdgcn_sched_barrier(0);                              \
        if (cp < 3 || (KK) < 16) {                                      \
            if ((KK) & 1) { RDA(ah1, al1, (KK) & 1);                    \
                            __builtin_amdgcn_sched_barrier(0);          \
                            RDB(bh1, bl1, DI2, DJ2, CSEL2); }           \
            else          { RDA(ah0, al0, (KK) & 1);                    \
                            __builtin_amdgcn_sched_barrier(0);          \
                            RDB(bh0, bl0, DI2, DJ2, CSEL2); }           \
        }                                                               \
        asm volatile("s_waitcnt lgkmcnt(15)" ::: "memory");             \
        __builtin_amdgcn_sched_barrier(0);                              \
        if (cp < 3 || (KK) < 14) DMAW((KK) & 1);                        \
        if ((O) == 1) { if ((KK) == 1 || cp < 3) DMAB(((KK) == 1) ? 1 : 0); } \
        __builtin_amdgcn_sched_barrier(0);                              \
    } while (0)

#pragma unroll 1
    for (int cp = 0; cp < 4; ++cp) {
        BODY(0, 0, 0, 0, 2, 0);  BODY(1, 1, 0, 1, 0, 0);  BODY(2, 2, 0, 1, 1, 1);
        BODY(3, 3, 0, 1, 2, 1);  BODY(4, 4, 0, 2, 0, 0);  BODY(5, 5, 0, 2, 1, 0);
        BODY(6, 6, 0, 2, 2, 0);  BODY(7, 7, 1, 0, 0, 0);  BODY(8, 8, 1, 0, 1, 0);
        BODY(9, 0, 1, 0, 2, 0);  BODY(10, 1, 1, 1, 0, 0); BODY(11, 2, 1, 1, 1, 1);
        BODY(12, 3, 1, 1, 2, 1); BODY(13, 4, 1, 2, 0, 0); BODY(14, 5, 1, 2, 1, 0);
        BODY(15, 6, 1, 2, 2, 0); BODY(16, 7, 0, 0, 0, 0); BODY(17, 8, 0, 0, 1, 0);
    }
#undef BODY

    // ---- epilogue: store f32 partial [256d][128l]
    float* pt = part + (((size_t)iid * 32 + lt) * 2 + ks) * 32768;
#pragma unroll
    for (int rg = 0; rg < 2; rg++)
#pragma unroll
        for (int cg = 0; cg < 8; cg++) {
            int l = cg * 16 + fr;
            int d0 = w * 32 + rg * 16 + fs * 4;
#pragma unroll
            for (int r = 0; r < 4; r++)
                pt[(d0 + r) * 128 + l] = acc[rg][cg][r];
        }
#undef PREP
#undef GLL
#undef DMAW
#undef DMAB
#undef RDA
#undef RDB
#undef DOMFMA
}

// ---------------- Kernel 1b: sum K-halves + D-norm + emit swizzled f16 hi/lo rows
__global__ __launch_bounds__(256) void norm_split(const float* __restrict__ part,
                                                  char* __restrict__ qemb,
                                                  char* __restrict__ kemb) {
    __shared__ float sm[4][64];
    __shared__ float invn[64];
    __shared__ char stage[64][1040];

    int iid = blockIdx.y;
    int bx  = blockIdx.x;
    int lt  = bx >> 1, lh2 = bx & 1;
    const float* p0 = part + (((size_t)iid * 32 + lt) * 2 + 0) * 32768 + lh2 * 64;
    const float* p1 = p0 + 32768;
    int t = threadIdx.x;
    int ll = t & 63, dq = t >> 6;

    float v[64];
    float sq = 0.f;
#pragma unroll
    for (int dd = 0; dd < 64; ++dd) {
        int d = dq * 64 + dd;
        float x = p0[d * 128 + ll] + p1[d * 128 + ll];
        v[dd] = x;
        sq += x * x;
    }
    sm[dq][ll] = sq;
    __syncthreads();
    if (t < 64) {
        float s = sm[0][t] + sm[1][t] + sm[2][t] + sm[3][t];
        invn[t] = 1.0f / fmaxf(sqrtf(s), 1e-12f);
    }
    __syncthreads();

    float sc = invn[ll];
    int swb = (ll & 7) << 4;
#pragma unroll
    for (int oc = 0; oc < 8; ++oc) {
        int d0 = dq * 64 + oc * 8;
        f16x8 h8, l8;
#pragma unroll
        for (int j = 0; j < 8; ++j) {
            float x = v[oc * 8 + j] * sc;
            half_t h = (half_t)x;
            h8[j] = h;
            l8[j] = (half_t)(x - (float)h);
        }
        int itb = d0 >> 5;
        int fsc = (d0 >> 3) & 3;
        *(f16x8*)&stage[ll][itb * 128 + ((fsc * 16) ^ swb)] = h8;
        *(f16x8*)&stage[ll][itb * 128 + ((64 + fsc * 16) ^ swb)] = l8;
    }
    __syncthreads();

    int b = iid & 1, type = iid >> 1;
    char* e = (type ? kemb : qemb);
    int rr = t >> 2, c0 = t & 3;
    char* erow = e + ((size_t)b * LL + lt * 128 + lh2 * 64 + rr) * 1024;
    const char* srow = &stage[rr][0];
#pragma unroll
    for (int c = 0; c < 16; ++c) {
        int cj = c0 + c * 4;
        *(float4*)(erow + cj * 16) = *(const float4*)(srow + cj * 16);
    }
}

// ---------------- Kernel 2: zero init (packed max buffer + zero page)
__global__ void init_packed(unsigned long long* p, int n) {
    int i = blockIdx.x * 256 + threadIdx.x;
    if (i < n) p[i] = 0ull;
}

// ---------------- Kernel 3: corr via LDS-staged split-3 MFMA + fused max/argmax
__global__ __launch_bounds__(256, 2) void corr_max_mfma(const char* __restrict__ kemb,
                                                        const char* __restrict__ qemb,
                                                        unsigned long long* __restrict__ packed) {
    __shared__ char sA[2][16384];
    __shared__ char sBq[2][16384];

    int b  = blockIdx.z;
    int l0 = blockIdx.y * 128;
    int m0 = blockIdx.x * 128;
    int t  = threadIdx.x;
    int w = t >> 6, lane = t & 63;
    int wr = w >> 1, wc = w & 1;
    int fr = lane & 15, fs = lane >> 4;

    const char* Abase = kemb + ((size_t)b * LL + l0) * 1024;
    const char* Bbase = qemb + ((size_t)b * LL + m0) * 1024;

    f32x4 acc[4][4];
#pragma unroll
    for (int i = 0; i < 4; i++)
#pragma unroll
        for (int j = 0; j < 4; j++) acc[i][j] = (f32x4){0.f, 0.f, 0.f, 0.f};

#define DMA2(bufi, itv)                                                   \
    do {                                                                  \
        _Pragma("unroll")                                                 \
        for (int c = 0; c < 4; c++) {                                     \
            int idx = c * 4096 + t * 16;                                  \
            int row = idx >> 7, offb = idx & 127;                         \
            __builtin_amdgcn_global_load_lds(                             \
                (const __attribute__((address_space(1))) void*)(Abase + (size_t)row * 1024 + (itv) * 128 + offb), \
                (__attribute__((address_space(3))) void*)(&sA[bufi][idx]), 16, 0, 0); \
        }                                                                 \
        _Pragma("unroll")                                                 \
        for (int c = 0; c < 4; c++) {                                     \
            int idx = c * 4096 + t * 16;                                  \
            int row = idx >> 7, offb = idx & 127;                         \
            __builtin_amdgcn_global_load_lds(                             \
                (const __attribute__((address_space(1))) void*)(Bbase + (size_t)row * 1024 + (itv) * 128 + offb), \
                (__attribute__((address_space(3))) void*)(&sBq[bufi][idx]), 16, 0, 0); \
        }                                                                 \
    } while (0)

    DMA2(0, 0);

    f16x8 ah[4], al[4], bh[4], bl[4];
    for (int it = 0; it < 8; ++it) {
        asm volatile("s_waitcnt vmcnt(0) lgkmcnt(0)" ::: "memory");
        __builtin_amdgcn_s_barrier();
        __builtin_amdgcn_sched_barrier(0);
        if (it < 7) DMA2((it + 1) & 1, it + 1);
        __builtin_amdgcn_sched_barrier(0);
        const char* sa = sA[it & 1];
        const char* sb = sBq[it & 1];
#pragma unroll
        for (int rg = 0; rg < 4; rg++) {
            int r = wr * 64 + rg * 16 + fr;
            const char* rp = sa + r * 128;
            int sw_ = (r & 7) << 4;
            ah[rg] = *(const f16x8*)(rp + ((fs * 16) ^ sw_));
            al[rg] = *(const f16x8*)(rp + ((64 + fs * 16) ^ sw_));
        }
#pragma unroll
        for (int cg = 0; cg < 4; cg++) {
            int r = wc * 64 + cg * 16 + fr;
            const char* rp = sb + r * 128;
            int sw_ = (r & 7) << 4;
            bh[cg] = *(const f16x8*)(rp + ((fs * 16) ^ sw_));
            bl[cg] = *(const f16x8*)(rp + ((64 + fs * 16) ^ sw_));
        }
#pragma unroll
        for (int rg = 0; rg < 4; rg++)
#pragma unroll
            for (int cg = 0; cg < 4; cg++)
                acc[rg][cg] = __builtin_amdgcn_mfma_f32_16x16x32_f16(ah[rg], bh[cg], acc[rg][cg], 0, 0, 0);
#pragma unroll
        for (int rg = 0; rg < 4; rg++)
#pragma unroll
            for (int cg = 0; cg < 4; cg++) {
                acc[rg][cg] = __builtin_amdgcn_mfma_f32_16x16x32_f16(ah[rg], bl[cg], acc[rg][cg], 0, 0, 0);
                acc[rg][cg] = __builtin_amdgcn_mfma_f32_16x16x32_f16(al[rg], bh[cg], acc[rg][cg], 0, 0, 0);
            }
    }
#undef DMA2

#pragma unroll
    for (int cg = 0; cg < 4; cg++) {
        unsigned long long best = 0ull;
#pragma unroll
        for (int rg = 0; rg < 4; rg++) {
#pragma unroll
            for (int r = 0; r < 4; r++) {
                unsigned u = __float_as_uint(acc[rg][cg][r]);
                u = (u & 0x80000000u) ? ~u : (u | 0x80000000u);
                int l = l0 + wr * 64 + rg * 16 + fs * 4 + r;
                unsigned long long p = ((unsigned long long)u << 32) | (unsigned)(4095 - l);
                best = (p > best) ? p : best;
            }
        }
        unsigned long long oo;
        oo = __shfl_xor(best, 16); best = (oo > best) ? oo : best;
        oo = __shfl_xor(best, 32); best = (oo > best) ? oo : best;
        if (lane < 16)
            atomicMax(&packed[(size_t)b * LL + m0 + wc * 64 + cg * 16 + lane], best);
    }
}

// ---------------- Kernel 4: decode packed -> S (d_out) + argmax (ws)
__global__ void decode_packed(const unsigned long long* __restrict__ packed,
                              float* __restrict__ S_out, int* __restrict__ arg) {
    int i = blockIdx.x * 256 + threadIdx.x;
    if (i < BB * LL) {
        unsigned long long p = packed[i];
        unsigned u = (unsigned)(p >> 32);
        unsigned bits = (u & 0x80000000u) ? (u & 0x7FFFFFFFu) : ~u;
        S_out[i] = __uint_as_float(bits);
        arg[i] = 4095 - (int)(unsigned)(p & 0xFFFFFFFFull);
    }
}

// ---------------- Kernel 5/7: batched 2D transpose src[R][Cc] -> dst[Cc][R]
__global__ __launch_bounds__(256) void transpose_mat(const float* __restrict__ src,
                                                     float* __restrict__ dst,
                                                     int R, int Cc) {
    __shared__ float tile[32][33];
    size_t boff = (size_t)blockIdx.z * R * Cc;
    int bx = blockIdx.x;
    int by = blockIdx.y;
    int tx = threadIdx.x & 31;
    int ty = threadIdx.x >> 5;
    const float* s = src + boff;
    float* d = dst + boff;
#pragma unroll
    for (int i = 0; i < 4; i++) {
        int r = by * 32 + ty + i * 8;
        int c = bx * 32 + tx;
        tile[ty + i * 8][tx] = s[(size_t)r * Cc + c];
    }
    __syncthreads();
#pragma unroll
    for (int i = 0; i < 4; i++) {
        int c = bx * 32 + ty + i * 8;
        int r = by * 32 + tx;
        d[(size_t)c * R + r] = tile[tx][ty + i * 8];
    }
}

// ---------------- Kernel 6: gather + fold (channel-last), one pixel per block
__global__ __launch_bounds__(256) void gather_fold(const float* __restrict__ value_t,
                                                   const int* __restrict__ arg,
                                                   float* __restrict__ T_t) {
    int b = blockIdx.y;
    int pix = blockIdx.x;
    int y = pix >> 6, x = pix & 63;
    int t = threadIdx.x;
    float2 acc = make_float2(0.f, 0.f);
    int cnty = (y == 0 || y == HH - 1) ? 2 : 3;
    int cntx = (x == 0 || x == WW - 1) ? 2 : 3;
    const int* ab = arg + b * LL;
    const float* vb = value_t + (size_t)b * LL * CC;
#pragma unroll
    for (int di = 0; di < 3; di++) {
        int my = y + 1 - di;
        if (my < 0 || my >= HH) continue;
#pragma unroll
        for (int dj = 0; dj < 3; dj++) {
            int mx = x + 1 - dj;
            if (mx < 0 || mx >= WW) continue;
            int a = ab[my * WW + mx];
            int ay = a >> 6, ax = a & 63;
            int vy = ay + di - 1, vx = ax + dj - 1;
            if (vy < 0 || vy >= HH || vx < 0 || vx >= WW) continue;
            float2 v = *(const float2*)&vb[((size_t)(vy * WW + vx)) * CC + t * 2];
            acc.x += v.x; acc.y += v.y;
        }
    }
    float inv = 1.0f / (float)(cnty * cntx);
    acc.x *= inv; acc.y *= inv;
    *(float2*)&T_t[((size_t)b * LL + pix) * CC + t * 2] = acc;
}

extern "C" void kernel_launch(void* const* d_in, const int* in_sizes, int n_in,
                              void* d_out, int out_size, void* d_ws, size_t ws_size,
                              hipStream_t stream) {
    const float* query = (const float*)d_in[0];
    const float* key   = (const float*)d_in[1];
    const float* value = (const float*)d_in[2];
    const float* Wemb  = (const float*)d_in[3];

    float* out   = (float*)d_out;
    float* S_out = out;
    float* T_out = out + BB * LL;

    char* ws = (char*)d_ws;
    char*  img_ts = ws;                                  // 33,554,432 (dead after embed)
    char*  Wst    = ws + 33554432;                       //  4,718,592 (dead after embed)
    float* part   = (float*)(ws + 38273024);             // 33,554,432 (dead after norm_split)
    char*  qemb   = ws + 71827456;                       //  8,388,608 (dead after corr)
    char*  kemb   = ws + 80216064;                       //  8,388,608 (dead after corr)
    unsigned long long* packed = (unsigned long long*)(ws + 88604672);  // 65,536
    char*  zp     = ws + 88670208;                       //  4,096 (zeroed page)
    int*   arg    = (int*)(ws + 88674304);               // 32,768
    float* val_t  = (float*)(ws + 38273024);             // alias part[0:16.78MB]
    float* T_t    = (float*)(ws + 38273024 + 16777216);  // alias part[16.78:33.55MB]

    init_packed   <<<dim3(34), 256, 0, stream>>>(packed, 8704);  // packed + zp
    presplit      <<<dim3(64, 4), 256, 0, stream>>>(query, key, img_ts);
    splitW2b      <<<dim3(576), 256, 0, stream>>>(Wemb, Wst);
    embed_mfma    <<<dim3(32, 4, 2), 512, 0, stream>>>(img_ts, Wst, zp, part);
    norm_split    <<<dim3(64, 4), 256, 0, stream>>>(part, qemb, kemb);
    corr_max_mfma <<<dim3(32, 32, 2), 256, 0, stream>>>(kemb, qemb, packed);
    decode_packed <<<dim3(32), 256, 0, stream>>>(packed, S_out, arg);
    transpose_mat <<<dim3(128, 16, 2), 256, 0, stream>>>(value, val_t, CC, LL);
    gather_fold   <<<dim3(4096, 2), 256, 0, stream>>>(val_t, arg, T_t);
    transpose_mat <<<dim3(16, 128, 2), 256, 0, stream>>>(T_t, T_out, LL, CC);
}

// Round 18
// 208.524 us; speedup vs baseline: 1.2523x; 1.2523x over previous
//
#include <hip/hip_runtime.h>
#include <hip/hip_bf16.h>
#include <stdint.h>
#include <math.h>

#define BB 2
#define CC 512
#define HH 64
#define WW 64
#define LL 4096
#define DD 256
#define CIN 4608   // 512*9
#define NG 144     // gates = 16 c-chunks x 9 offsets

typedef _Float16 half_t;
typedef __attribute__((ext_vector_type(8))) _Float16 f16x8;
typedef __attribute__((ext_vector_type(4))) _Float16 f16x4;
typedef __attribute__((ext_vector_type(4))) float f32x4;

// ---------------- Kernel A: presplit images -> channel-last f16 hi/lo, swizzled
// img_ts layout: [img 4][y 64][cc 16][x 64][128B]; within 128B, phys 16B slot p
// holds logical slot (p ^ (x&7)).
__global__ __launch_bounds__(256) void presplit(const float* __restrict__ query,
                                                const float* __restrict__ key,
                                                char* __restrict__ img_ts) {
    __shared__ float tile[32][65];
    int img = blockIdx.y;               // b = img&1, type = img>>1
    int y   = blockIdx.x;
    const float* src = ((img >> 1) ? key : query) + (size_t)(img & 1) * CC * LL + y * WW;
    char* dstbase = img_ts + ((size_t)img * 64 + y) * (16 * 64 * 128);
    int t = threadIdx.x;
    int xl = t & 63, c4 = t >> 6;
    int xw = t >> 2, fsw = t & 3;
    for (int cc = 0; cc < 16; ++cc) {
#pragma unroll
        for (int j = 0; j < 8; ++j) {
            int cl = c4 + j * 4;
            tile[cl][xl] = src[(size_t)(cc * 32 + cl) * LL + xl];
        }
        __syncthreads();
        f16x8 h8, l8;
#pragma unroll
        for (int j = 0; j < 8; ++j) {
            float v = tile[fsw * 8 + j][xw];
            half_t h = (half_t)v;
            h8[j] = h; l8[j] = (half_t)(v - (float)h);
        }
        char* p = dstbase + (size_t)cc * 8192 + xw * 128;
        int swz = (xw & 7) << 4;
        *(f16x8*)(p + ((fsw * 16) ^ swz)) = h8;
        *(f16x8*)(p + ((64 + fsw * 16) ^ swz)) = l8;
        __syncthreads();
    }
}

// ---------------- Kernel B: repack W into per-gate tiles [g = cc*9+o][d][128B]
__global__ __launch_bounds__(256) void splitW2b(const float* __restrict__ W,
                                                char* __restrict__ Wst) {
    int i = blockIdx.x * 256 + threadIdx.x;   // NG*DD*4 = 147456
    if (i >= NG * DD * 4) return;
    int g  = i >> 10;
    int r  = i & 1023;
    int d  = r >> 2;
    int fs = r & 3;
    int cc = g / 9, o = g - cc * 9;
    const float* src = W + (size_t)d * CIN;
    f16x8 h8, l8;
#pragma unroll
    for (int j = 0; j < 8; j++) {
        float w = src[(cc * 32 + fs * 8 + j) * 9 + o];
        half_t h = (half_t)w;
        h8[j] = h;
        l8[j] = (half_t)(w - (float)h);
    }
    size_t base = (size_t)g * 32768 + d * 128;
    int sw = (d & 7) << 4;
    *(f16x8*)(Wst + base + ((fs * 16) ^ sw)) = h8;
    *(f16x8*)(Wst + base + ((64 + fs * 16) ^ sw)) = l8;
}

// ---------------- Kernel 1: embed, offset-decomposed, K-split x2.
// Block 256d x 128l, 8 waves; wave = 32d x 128l (WAVE-PRIVATE W rows).
// Barrier-free gates: per-wave counted vmcnt fences for wave-private W DMA;
// barriers only at B-chunk boundaries (8 total). 9-offset inner loop fully
// unrolled -> all ds_read offsets are compile-time immediates (zero VALU).
// (Round-14 verified: 93.5us, MfmaUtil 56%, absmax 0.0. Rounds 15-17's
// 2-body-ahead variant spilled to scratch -- VGPR is the binding resource.)
__global__ __launch_bounds__(512, 2) void embed_mfma(const char* __restrict__ img_ts,
                                                     const char* __restrict__ Wst,
                                                     const char* __restrict__ zp,
                                                     float* __restrict__ part) {
    __shared__ char sW[2][32768];       // W gate tiles (swizzled); wave w owns bytes w*4096..+4095
    __shared__ char sB[2][33792];       // B tiles: [ri 4][xi 66][128B]

    int iid = blockIdx.y;               // image 0..3
    int ks  = blockIdx.z;               // K half 0..1
    int lt  = blockIdx.x;               // l-tile 0..31
    int y0  = lt * 2;                   // first image row of tile
    int t = threadIdx.x;
    int w = t >> 6, lane = t & 63;
    int fr = lane & 15, fs = lane >> 4;

    // B-DMA sources (cross-wave distributed; 5th call only wave 0)
    const char* imgb = img_ts + (size_t)iid * (64 * 16 * 64 * 128) + (size_t)ks * 65536;
    const char *ps0, *ps1, *ps2, *ps3, *ps4;
    int pb0, pb1, pb2, pb3, pb4;
#define PREP(qv, PS, PB)                                                \
    {                                                                   \
        int q = (qv);                                                   \
        int ri = q / 528;                                               \
        int rem = q - ri * 528;                                         \
        int xi = rem >> 3, sub = rem & 7;                               \
        int xg = xi - 1, yg = y0 - 1 + ri;                              \
        bool ok = (yg >= 0) && (yg < 64) && (xg >= 0) && (xg < 64);     \
        PS = ok ? imgb + (size_t)yg * 131072 + (size_t)xg * 128 + sub * 16 \
                : zp + ((q & 255) * 16);                                \
        PB = ok ? 8192 : 0;                                             \
    }
    PREP(t, ps0, pb0); PREP(512 + t, ps1, pb1); PREP(1024 + t, ps2, pb2);
    PREP(1536 + t, ps3, pb3); PREP(2048 + t, ps4, pb4);

    // W per-wave DMA pointers: wave w copies its 4KB slice (rows w*32..+31)
    const char* pWl = Wst + (size_t)ks * 72 * 32768 + (w << 12) + lane * 16;
    char* wdst0 = &sW[0][0] + (w << 12) + lane * 16;
    char* wdst1 = wdst0 + 32768;
    char* bB0 = &sB[0][0] + t * 16;

    // A ds_read bases (per-lane; rg/bufsel via immediate)
    int swzA = (fr & 7) << 4;
    const char* aBH = &sW[0][0] + (w << 12) + fr * 128 + ((fs * 16) ^ swzA);
    const char* aBL = &sW[0][0] + (w << 12) + fr * 128 + ((64 + fs * 16) ^ swzA);
    // B ds_read bases per dj (ri/cg/bufsel via immediate)
    const char* bH0 = &sB[0][0] + (fr + 0) * 128 + ((fs * 16) ^ (((fr - 1) & 7) << 4));
    const char* bL0 = &sB[0][0] + (fr + 0) * 128 + (((64 + fs * 16)) ^ (((fr - 1) & 7) << 4));
    const char* bH1 = &sB[0][0] + (fr + 1) * 128 + ((fs * 16) ^ (((fr) & 7) << 4));
    const char* bL1 = &sB[0][0] + (fr + 1) * 128 + (((64 + fs * 16)) ^ (((fr) & 7) << 4));
    const char* bH2 = &sB[0][0] + (fr + 2) * 128 + ((fs * 16) ^ (((fr + 1) & 7) << 4));
    const char* bL2 = &sB[0][0] + (fr + 2) * 128 + (((64 + fs * 16)) ^ (((fr + 1) & 7) << 4));

#define GLL(src, dst)                                                   \
    __builtin_amdgcn_global_load_lds(                                   \
        (const __attribute__((address_space(1))) void*)(src),           \
        (__attribute__((address_space(3))) void*)(dst), 16, 0, 0)

#define DMAW(SEL)                                                       \
    do {                                                                \
        char* wd_ = (SEL) ? wdst1 : wdst0;                              \
        GLL(pWl, wd_);                                                  \
        GLL(pWl + 1024, wd_ + 1024);                                    \
        GLL(pWl + 2048, wd_ + 2048);                                    \
        GLL(pWl + 3072, wd_ + 3072);                                    \
        pWl += 32768;                                                   \
    } while (0)

#define DMAB(SEL)                                                       \
    do {                                                                \
        char* bd_ = bB0 + (SEL) * 33792;                                \
        GLL(ps0, bd_);                                                  \
        GLL(ps1, bd_ + 8192);                                           \
        GLL(ps2, bd_ + 16384);                                          \
        GLL(ps3, bd_ + 24576);                                          \
        if (t < 64) GLL(ps4, bd_ + 32768);                              \
        ps0 += pb0; ps1 += pb1; ps2 += pb2; ps3 += pb3; ps4 += pb4;     \
    } while (0)

#define RDA(AH, AL, BSEL)                                               \
    do {                                                                \
        AH[0] = *(const f16x8*)(aBH + (BSEL) * 32768);                  \
        AL[0] = *(const f16x8*)(aBL + (BSEL) * 32768);                  \
        AH[1] = *(const f16x8*)(aBH + 2048 + (BSEL) * 32768);           \
        AL[1] = *(const f16x8*)(aBL + 2048 + (BSEL) * 32768);           \
    } while (0)

#define RDB(DI, DJ, CSEL)                                               \
    do {                                                                \
        const char* h_ = (DJ) == 0 ? bH0 : (DJ) == 1 ? bH1 : bH2;       \
        const char* l_ = (DJ) == 0 ? bL0 : (DJ) == 1 ? bL1 : bL2;       \
        _Pragma("unroll")                                               \
        for (int cg = 0; cg < 8; cg++) {                                \
            int imm = ((cg >> 2) + (DI)) * 8448 + (cg & 3) * 2048 + (CSEL) * 33792; \
            bh[cg] = *(const f16x8*)(h_ + imm);                         \
            bl[cg] = *(const f16x8*)(l_ + imm);                         \
        }                                                               \
    } while (0)

#define DOMFMA(AH, AL)                                                  \
    do {                                                                \
        _Pragma("unroll")                                               \
        for (int rg = 0; rg < 2; rg++)                                  \
            _Pragma("unroll")                                           \
            for (int cg = 0; cg < 8; cg++)                              \
                acc[rg][cg] = __builtin_amdgcn_mfma_f32_16x16x32_f16(AH[rg], bh[cg], acc[rg][cg], 0, 0, 0); \
        _Pragma("unroll")                                               \
        for (int rg = 0; rg < 2; rg++)                                  \
            _Pragma("unroll")                                           \
            for (int cg = 0; cg < 8; cg++) {                            \
                acc[rg][cg] = __builtin_amdgcn_mfma_f32_16x16x32_f16(AH[rg], bl[cg], acc[rg][cg], 0, 0, 0); \
                acc[rg][cg] = __builtin_amdgcn_mfma_f32_16x16x32_f16(AL[rg], bh[cg], acc[rg][cg], 0, 0, 0); \
            }                                                           \
    } while (0)

    f32x4 acc[2][8];
#pragma unroll
    for (int rg = 0; rg < 2; rg++)
#pragma unroll
        for (int cg = 0; cg < 8; cg++) acc[rg][cg] = (f32x4){0.f, 0.f, 0.f, 0.f};

    f16x8 ah0[2], al0[2], ah1[2], al1[2];
    f16x8 bh[8], bl[8];

    // ---- prologue: B(0), W(0), W(1); own B+W(0) retired; A(0)->set0
    DMAB(0);
    DMAW(0);
    DMAW(1);
    asm volatile("s_waitcnt vmcnt(4)" ::: "memory");   // W(0)+B(0)(own) retired; W(1) may fly
    __builtin_amdgcn_sched_barrier(0);
    RDA(ah0, al0, 0);
    __builtin_amdgcn_sched_barrier(0);

    // per-gate: lgkm(0) [frees buffer for DMAW overwrite] ; DMAW(g+2) [; DMAB]
    // ; vmcnt(N) [W(g+1) resident: N=8 at o==1,2 (own B in flight), else 4]
    // ; read A(g+1)+B(g) ; MFMA(g) from registers.
#define BODY(KK, O, CSEL, NSEL, DI, DJ)                                 \
    do {                                                                \
        if ((O) == 0) __builtin_amdgcn_s_barrier();                     \
        asm volatile("s_waitcnt lgkmcnt(0)" ::: "memory");              \
        __builtin_amdgcn_sched_barrier(0);                              \
        DMAW((KK) & 1);                                                 \
        if ((O) == 1) DMAB(NSEL);                                       \
        if ((O) == 1 || (O) == 2)                                       \
            asm volatile("s_waitcnt vmcnt(8)" ::: "memory");            \
        else                                                            \
            asm volatile("s_waitcnt vmcnt(4)" ::: "memory");            \
        __builtin_amdgcn_sched_barrier(0);                              \
        if ((KK) & 1) { RDA(ah0, al0, ((KK) + 1) & 1); }                \
        else          { RDA(ah1, al1, ((KK) + 1) & 1); }                \
        RDB(DI, DJ, CSEL);                                              \
        __builtin_amdgcn_sched_barrier(0);                              \
        if ((KK) & 1) DOMFMA(ah1, al1); else DOMFMA(ah0, al0);          \
    } while (0)

#pragma unroll 1
    for (int cp = 0; cp < 4; ++cp) {
        BODY(0, 0, 0, 1, 0, 0);  BODY(1, 1, 0, 1, 0, 1);  BODY(2, 2, 0, 1, 0, 2);
        BODY(3, 3, 0, 1, 1, 0);  BODY(4, 4, 0, 1, 1, 1);  BODY(5, 5, 0, 1, 1, 2);
        BODY(6, 6, 0, 1, 2, 0);  BODY(7, 7, 0, 1, 2, 1);  BODY(8, 8, 0, 1, 2, 2);
        BODY(9, 0, 1, 0, 0, 0);  BODY(10, 1, 1, 0, 0, 1); BODY(11, 2, 1, 0, 0, 2);
        BODY(12, 3, 1, 0, 1, 0); BODY(13, 4, 1, 0, 1, 1); BODY(14, 5, 1, 0, 1, 2);
        BODY(15, 6, 1, 0, 2, 0); BODY(16, 7, 1, 0, 2, 1); BODY(17, 8, 1, 0, 2, 2);
    }
#undef BODY

    // ---- epilogue: store f32 partial [256d][128l]
    float* pt = part + (((size_t)iid * 32 + lt) * 2 + ks) * 32768;
#pragma unroll
    for (int rg = 0; rg < 2; rg++)
#pragma unroll
        for (int cg = 0; cg < 8; cg++) {
            int l = cg * 16 + fr;
            int d0 = w * 32 + rg * 16 + fs * 4;
#pragma unroll
            for (int r = 0; r < 4; r++)
                pt[(d0 + r) * 128 + l] = acc[rg][cg][r];
        }
#undef PREP
#undef GLL
#undef DMAW
#undef DMAB
#undef RDA
#undef RDB
#undef DOMFMA
}

// ---------------- Kernel 1b: sum K-halves + D-norm + emit swizzled f16 hi/lo rows
__global__ __launch_bounds__(256) void norm_split(const float* __restrict__ part,
                                                  char* __restrict__ qemb,
                                                  char* __restrict__ kemb) {
    __shared__ float sm[4][64];
    __shared__ float invn[64];
    __shared__ char stage[64][1040];

    int iid = blockIdx.y;
    int bx  = blockIdx.x;
    int lt  = bx >> 1, lh2 = bx & 1;
    const float* p0 = part + (((size_t)iid * 32 + lt) * 2 + 0) * 32768 + lh2 * 64;
    const float* p1 = p0 + 32768;
    int t = threadIdx.x;
    int ll = t & 63, dq = t >> 6;

    float v[64];
    float sq = 0.f;
#pragma unroll
    for (int dd = 0; dd < 64; ++dd) {
        int d = dq * 64 + dd;
        float x = p0[d * 128 + ll] + p1[d * 128 + ll];
        v[dd] = x;
        sq += x * x;
    }
    sm[dq][ll] = sq;
    __syncthreads();
    if (t < 64) {
        float s = sm[0][t] + sm[1][t] + sm[2][t] + sm[3][t];
        invn[t] = 1.0f / fmaxf(sqrtf(s), 1e-12f);
    }
    __syncthreads();

    float sc = invn[ll];
    int swb = (ll & 7) << 4;
#pragma unroll
    for (int oc = 0; oc < 8; ++oc) {
        int d0 = dq * 64 + oc * 8;
        f16x8 h8, l8;
#pragma unroll
        for (int j = 0; j < 8; ++j) {
            float x = v[oc * 8 + j] * sc;
            half_t h = (half_t)x;
            h8[j] = h;
            l8[j] = (half_t)(x - (float)h);
        }
        int itb = d0 >> 5;
        int fsc = (d0 >> 3) & 3;
        *(f16x8*)&stage[ll][itb * 128 + ((fsc * 16) ^ swb)] = h8;
        *(f16x8*)&stage[ll][itb * 128 + ((64 + fsc * 16) ^ swb)] = l8;
    }
    __syncthreads();

    int b = iid & 1, type = iid >> 1;
    char* e = (type ? kemb : qemb);
    int rr = t >> 2, c0 = t & 3;
    char* erow = e + ((size_t)b * LL + lt * 128 + lh2 * 64 + rr) * 1024;
    const char* srow = &stage[rr][0];
#pragma unroll
    for (int c = 0; c < 16; ++c) {
        int cj = c0 + c * 4;
        *(float4*)(erow + cj * 16) = *(const float4*)(srow + cj * 16);
    }
}

// ---------------- Kernel 2: zero init (packed max buffer + zero page)
__global__ void init_packed(unsigned long long* p, int n) {
    int i = blockIdx.x * 256 + threadIdx.x;
    if (i < n) p[i] = 0ull;
}

// ---------------- Kernel 3: corr via LDS-staged split-3 MFMA + fused max/argmax
__global__ __launch_bounds__(256, 2) void corr_max_mfma(const char* __restrict__ kemb,
                                                        const char* __restrict__ qemb,
                                                        unsigned long long* __restrict__ packed) {
    __shared__ char sA[2][16384];
    __shared__ char sBq[2][16384];

    int b  = blockIdx.z;
    int l0 = blockIdx.y * 128;
    int m0 = blockIdx.x * 128;
    int t  = threadIdx.x;
    int w = t >> 6, lane = t & 63;
    int wr = w >> 1, wc = w & 1;
    int fr = lane & 15, fs = lane >> 4;

    const char* Abase = kemb + ((size_t)b * LL + l0) * 1024;
    const char* Bbase = qemb + ((size_t)b * LL + m0) * 1024;

    f32x4 acc[4][4];
#pragma unroll
    for (int i = 0; i < 4; i++)
#pragma unroll
        for (int j = 0; j < 4; j++) acc[i][j] = (f32x4){0.f, 0.f, 0.f, 0.f};

#define DMA2(bufi, itv)                                                   \
    do {                                                                  \
        _Pragma("unroll")                                                 \
        for (int c = 0; c < 4; c++) {                                     \
            int idx = c * 4096 + t * 16;                                  \
            int row = idx >> 7, offb = idx & 127;                         \
            __builtin_amdgcn_global_load_lds(                             \
                (const __attribute__((address_space(1))) void*)(Abase + (size_t)row * 1024 + (itv) * 128 + offb), \
                (__attribute__((address_space(3))) void*)(&sA[bufi][idx]), 16, 0, 0); \
        }                                                                 \
        _Pragma("unroll")                                                 \
        for (int c = 0; c < 4; c++) {                                     \
            int idx = c * 4096 + t * 16;                                  \
            int row = idx >> 7, offb = idx & 127;                         \
            __builtin_amdgcn_global_load_lds(                             \
                (const __attribute__((address_space(1))) void*)(Bbase + (size_t)row * 1024 + (itv) * 128 + offb), \
                (__attribute__((address_space(3))) void*)(&sBq[bufi][idx]), 16, 0, 0); \
        }                                                                 \
    } while (0)

    DMA2(0, 0);

    f16x8 ah[4], al[4], bh[4], bl[4];
    for (int it = 0; it < 8; ++it) {
        asm volatile("s_waitcnt vmcnt(0) lgkmcnt(0)" ::: "memory");
        __builtin_amdgcn_s_barrier();
        __builtin_amdgcn_sched_barrier(0);
        if (it < 7) DMA2((it + 1) & 1, it + 1);
        __builtin_amdgcn_sched_barrier(0);
        const char* sa = sA[it & 1];
        const char* sb = sBq[it & 1];
#pragma unroll
        for (int rg = 0; rg < 4; rg++) {
            int r = wr * 64 + rg * 16 + fr;
            const char* rp = sa + r * 128;
            int sw_ = (r & 7) << 4;
            ah[rg] = *(const f16x8*)(rp + ((fs * 16) ^ sw_));
            al[rg] = *(const f16x8*)(rp + ((64 + fs * 16) ^ sw_));
        }
#pragma unroll
        for (int cg = 0; cg < 4; cg++) {
            int r = wc * 64 + cg * 16 + fr;
            const char* rp = sb + r * 128;
            int sw_ = (r & 7) << 4;
            bh[cg] = *(const f16x8*)(rp + ((fs * 16) ^ sw_));
            bl[cg] = *(const f16x8*)(rp + ((64 + fs * 16) ^ sw_));
        }
#pragma unroll
        for (int rg = 0; rg < 4; rg++)
#pragma unroll
            for (int cg = 0; cg < 4; cg++)
                acc[rg][cg] = __builtin_amdgcn_mfma_f32_16x16x32_f16(ah[rg], bh[cg], acc[rg][cg], 0, 0, 0);
#pragma unroll
        for (int rg = 0; rg < 4; rg++)
#pragma unroll
            for (int cg = 0; cg < 4; cg++) {
                acc[rg][cg] = __builtin_amdgcn_mfma_f32_16x16x32_f16(ah[rg], bl[cg], acc[rg][cg], 0, 0, 0);
                acc[rg][cg] = __builtin_amdgcn_mfma_f32_16x16x32_f16(al[rg], bh[cg], acc[rg][cg], 0, 0, 0);
            }
    }
#undef DMA2

#pragma unroll
    for (int cg = 0; cg < 4; cg++) {
        unsigned long long best = 0ull;
#pragma unroll
        for (int rg = 0; rg < 4; rg++) {
#pragma unroll
            for (int r = 0; r < 4; r++) {
                unsigned u = __float_as_uint(acc[rg][cg][r]);
                u = (u & 0x80000000u) ? ~u : (u | 0x80000000u);
                int l = l0 + wr * 64 + rg * 16 + fs * 4 + r;
                unsigned long long p = ((unsigned long long)u << 32) | (unsigned)(4095 - l);
                best = (p > best) ? p : best;
            }
        }
        unsigned long long oo;
        oo = __shfl_xor(best, 16); best = (oo > best) ? oo : best;
        oo = __shfl_xor(best, 32); best = (oo > best) ? oo : best;
        if (lane < 16)
            atomicMax(&packed[(size_t)b * LL + m0 + wc * 64 + cg * 16 + lane], best);
    }
}

// ---------------- Kernel 4: decode packed -> S (d_out) + argmax (ws)
__global__ void decode_packed(const unsigned long long* __restrict__ packed,
                              float* __restrict__ S_out, int* __restrict__ arg) {
    int i = blockIdx.x * 256 + threadIdx.x;
    if (i < BB * LL) {
        unsigned long long p = packed[i];
        unsigned u = (unsigned)(p >> 32);
        unsigned bits = (u & 0x80000000u) ? (u & 0x7FFFFFFFu) : ~u;
        S_out[i] = __uint_as_float(bits);
        arg[i] = 4095 - (int)(unsigned)(p & 0xFFFFFFFFull);
    }
}

// ---------------- Kernel 5/7: batched 2D transpose src[R][Cc] -> dst[Cc][R]
__global__ __launch_bounds__(256) void transpose_mat(const float* __restrict__ src,
                                                     float* __restrict__ dst,
                                                     int R, int Cc) {
    __shared__ float tile[32][33];
    size_t boff = (size_t)blockIdx.z * R * Cc;
    int bx = blockIdx.x;
    int by = blockIdx.y;
    int tx = threadIdx.x & 31;
    int ty = threadIdx.x >> 5;
    const float* s = src + boff;
    float* d = dst + boff;
#pragma unroll
    for (int i = 0; i < 4; i++) {
        int r = by * 32 + ty + i * 8;
        int c = bx * 32 + tx;
        tile[ty + i * 8][tx] = s[(size_t)r * Cc + c];
    }
    __syncthreads();
#pragma unroll
    for (int i = 0; i < 4; i++) {
        int c = bx * 32 + ty + i * 8;
        int r = by * 32 + tx;
        d[(size_t)c * R + r] = tile[tx][ty + i * 8];
    }
}

// ---------------- Kernel 6: gather + fold (channel-last), one pixel per block
__global__ __launch_bounds__(256) void gather_fold(const float* __restrict__ value_t,
                                                   const int* __restrict__ arg,
                                                   float* __restrict__ T_t) {
    int b = blockIdx.y;
    int pix = blockIdx.x;
    int y = pix >> 6, x = pix & 63;
    int t = threadIdx.x;
    float2 acc = make_float2(0.f, 0.f);
    int cnty = (y == 0 || y == HH - 1) ? 2 : 3;
    int cntx = (x == 0 || x == WW - 1) ? 2 : 3;
    const int* ab = arg + b * LL;
    const float* vb = value_t + (size_t)b * LL * CC;
#pragma unroll
    for (int di = 0; di < 3; di++) {
        int my = y + 1 - di;
        if (my < 0 || my >= HH) continue;
#pragma unroll
        for (int dj = 0; dj < 3; dj++) {
            int mx = x + 1 - dj;
            if (mx < 0 || mx >= WW) continue;
            int a = ab[my * WW + mx];
            int ay = a >> 6, ax = a & 63;
            int vy = ay + di - 1, vx = ax + dj - 1;
            if (vy < 0 || vy >= HH || vx < 0 || vx >= WW) continue;
            float2 v = *(const float2*)&vb[((size_t)(vy * WW + vx)) * CC + t * 2];
            acc.x += v.x; acc.y += v.y;
        }
    }
    float inv = 1.0f / (float)(cnty * cntx);
    acc.x *= inv; acc.y *= inv;
    *(float2*)&T_t[((size_t)b * LL + pix) * CC + t * 2] = acc;
}

extern "C" void kernel_launch(void* const* d_in, const int* in_sizes, int n_in,
                              void* d_out, int out_size, void* d_ws, size_t ws_size,
                              hipStream_t stream) {
    const float* query = (const float*)d_in[0];
    const float* key   = (const float*)d_in[1];
    const float* value = (const float*)d_in[2];
    const float* Wemb  = (const float*)d_in[3];

    float* out   = (float*)d_out;
    float* S_out = out;
    float* T_out = out + BB * LL;

    char* ws = (char*)d_ws;
    char*  img_ts = ws;                                  // 33,554,432 (dead after embed)
    char*  Wst    = ws + 33554432;                       //  4,718,592 (dead after embed)
    float* part   = (float*)(ws + 38273024);             // 33,554,432 (dead after norm_split)
    char*  qemb   = ws + 71827456;                       //  8,388,608 (dead after corr)
    char*  kemb   = ws + 80216064;                       //  8,388,608 (dead after corr)
    unsigned long long* packed = (unsigned long long*)(ws + 88604672);  // 65,536
    char*  zp     = ws + 88670208;                       //  4,096 (zeroed page)
    int*   arg    = (int*)(ws + 88674304);               // 32,768
    float* val_t  = (float*)(ws + 38273024);             // alias part[0:16.78MB]
    float* T_t    = (float*)(ws + 38273024 + 16777216);  // alias part[16.78:33.55MB]

    init_packed   <<<dim3(34), 256, 0, stream>>>(packed, 8704);  // packed + zp
    presplit      <<<dim3(64, 4), 256, 0, stream>>>(query, key, img_ts);
    splitW2b      <<<dim3(576), 256, 0, stream>>>(Wemb, Wst);
    embed_mfma    <<<dim3(32, 4, 2), 512, 0, stream>>>(img_ts, Wst, zp, part);
    norm_split    <<<dim3(64, 4), 256, 0, stream>>>(part, qemb, kemb);
    corr_max_mfma <<<dim3(32, 32, 2), 256, 0, stream>>>(kemb, qemb, packed);
    decode_packed <<<dim3(32), 256, 0, stream>>>(packed, S_out, arg);
    transpose_mat <<<dim3(128, 16, 2), 256, 0, stream>>>(value, val_t, CC, LL);
    gather_fold   <<<dim3(4096, 2), 256, 0, stream>>>(val_t, arg, T_t);
    transpose_mat <<<dim3(16, 128, 2), 256, 0, stream>>>(T_t, T_out, LL, CC);
}